// Round 1
// baseline (45183.487 us; speedup 1.0000x reference)
//
#include <hip/hip_runtime.h>

constexpr int B = 4, S = 16, D = 1024, DN = 2048, NB = 4, K = 8, VOCAB = 151936;
constexpr int NSTEP = S * K * NB;  // 512 sequential (t,k,i) block-steps
constexpr int NBLK = 512;          // 2 blocks/CU on 256 CUs (48KB LDS each)

__device__ __forceinline__ float sigf(float x) { return 1.0f / (1.0f + expf(-x)); }
__device__ __forceinline__ float softplusf(float x) {
  return fmaxf(x, 0.0f) + log1pf(expf(-fabsf(x)));
}
__device__ __forceinline__ float dot4(float4 w, float4 v, float a) {
  return fmaf(w.x, v.x, fmaf(w.y, v.y, fmaf(w.z, v.z, fmaf(w.w, v.w, a))));
}

template <int N>
__device__ __forceinline__ void wred(float* a) {
#pragma unroll
  for (int m = 1; m < 64; m <<= 1) {
#pragma unroll
    for (int q = 0; q < N; ++q) a[q] += __shfl_xor(a[q], m, 64);
  }
}

// Two-level grid barrier. Monotonic counters (no reset -> no reset/arrive race).
// bar[0]: root counter; bar[16]: generation; bar[32 + g*16]: 64 group counters
// (cacheline-spaced). 512 blocks = 64 groups x 8. Agent-scope acq/rel gives
// cross-XCD visibility of plain stores made before the barrier.
__device__ __forceinline__ void gbar(int* bar, int epoch) {
  __syncthreads();
  if (threadIdx.x == 0) {
    int* gcnt = bar + 32 + ((blockIdx.x & 63) << 4);
    int a = __hip_atomic_fetch_add(gcnt, 1, __ATOMIC_ACQ_REL, __HIP_MEMORY_SCOPE_AGENT);
    if (((a + 1) & 7) == 0) {  // last of this group's 8 blocks this epoch
      int r = __hip_atomic_fetch_add(bar, 1, __ATOMIC_ACQ_REL, __HIP_MEMORY_SCOPE_AGENT);
      if (r + 1 == 64 * epoch)
        __hip_atomic_store(bar + 16, epoch, __ATOMIC_RELEASE, __HIP_MEMORY_SCOPE_AGENT);
    }
    while (__hip_atomic_load(bar + 16, __ATOMIC_RELAXED, __HIP_MEMORY_SCOPE_AGENT) < epoch)
      __builtin_amdgcn_s_sleep(2);
    (void)__hip_atomic_load(bar + 16, __ATOMIC_ACQUIRE, __HIP_MEMORY_SCOPE_AGENT);
  }
  __syncthreads();
}

// Persistent kernel: encoder+bits for all tokens, then 512 recurrent steps with
// 2 phases each. GV = [WbV;WaV;WtV] @ V for the NEXT step, computed one step
// ahead (double-buffered) so that every phase streams a balanced 24KB/wave.
__global__ __launch_bounds__(256, 2) void snn_main(
    const int* __restrict__ token_ids, const float* __restrict__ embed,
    const float* __restrict__ enc_W, const float* __restrict__ enc_b,
    const float* __restrict__ Win, const float* __restrict__ WbX,
    const float* __restrict__ WaX, const float* __restrict__ WtX,
    const float* __restrict__ WbV, const float* __restrict__ WaV,
    const float* __restrict__ WtV,
    const float* __restrict__ b_beta, const float* __restrict__ b_alpha,
    const float* __restrict__ b_th,
    const float* __restrict__ Wgate, const float* __restrict__ Wskip,
    const float* __restrict__ Wout,
    const float* __restrict__ plif_w, const float* __restrict__ out_vth,
    float* __restrict__ frames, float* __restrict__ sp, float* __restrict__ sbuf,
    float* __restrict__ V, float* __restrict__ u, float* __restrict__ GV,
    float* __restrict__ decoded, int* bar) {
  __shared__ float lds[B * D + B * DN];  // 48KB: sS (16KB) + sX (32KB)
  float* sS = lds;
  float* sX = lds + B * D;

  const int lane = threadIdx.x & 63;
  const int warp = threadIdx.x >> 6;
  const int gw = (blockIdx.x << 2) + warp;  // 0..2047: one wave per row
  int epoch = 0;

  // ---------- encoder + bit frames, all 16 tokens up front (no recurrence) ----------
  {
    const int d = gw & 1023;
    const int t0 = gw >> 10;  // 0..1
    const float4* wrow = (const float4*)(enc_W + (size_t)d * D);
    for (int rep = 0; rep < 8; ++rep) {
      const int t = t0 * 8 + rep;
      float a[4] = {0.f, 0.f, 0.f, 0.f};
      int ids[4];
#pragma unroll
      for (int b = 0; b < 4; ++b) ids[b] = token_ids[b * S + t];
#pragma unroll
      for (int c = lane; c < D / 4; c += 64) {
        float4 w = wrow[c];
#pragma unroll
        for (int b = 0; b < 4; ++b) {
          float4 e = ((const float4*)(embed + (size_t)ids[b] * D))[c];
          a[b] = dot4(w, e, a[b]);
        }
      }
      wred<4>(a);
      if (lane == 0) {
        float eb = enc_b[d];
#pragma unroll
        for (int b = 0; b < 4; ++b) {
          float res = sigf(a[b] + eb);
#pragma unroll
          for (int k = 0; k < K; ++k) {
            float bit = (res >= 0.5f) ? 1.0f : 0.0f;
            frames[((size_t)(t * K + k) * B + b) * D + d] = bit;
            res = (res - 0.5f * bit) * 2.0f;
          }
        }
      }
    }
  }
  gbar(bar, ++epoch);

  float dec[4] = {0.f, 0.f, 0.f, 0.f};  // per-(b) decode accumulator (PU lane0)

  for (int n = 0; n < NSTEP; ++n) {
    const int i = n & 3;
    const int kk = (n >> 2) & 7;
    const int t = n >> 5;
    const int i2 = (n + 1) & 3;          // block whose GV we produce this step
    const bool doVU = (n + 1 < NSTEP);
    const int par_r = n & 1, par_w = par_r ^ 1;
    const float* s_read = (i == 0) ? frames + (size_t)(t * K + kk) * B * D
                                   : sbuf + (size_t)(n & 1) * B * D;

    // ================= PHASE A: X-gates(i) + WbV(i2) + combine =================
    for (int idx = threadIdx.x; idx < (B * D) / 4; idx += 256)
      ((float4*)sS)[idx] = ((const float4*)s_read)[idx];
    if (doVU)
      for (int idx = threadIdx.x; idx < (B * DN) / 4; idx += 256)
        ((float4*)sX)[idx] = ((const float4*)(V + (size_t)i2 * B * DN))[idx];
    __syncthreads();

    {
      const int j = gw;
      // [0..3]=beta [4..7]=alpha [8..11]=th [12..15]=in [16..19]=WbV(i2)
      float acc[20];
#pragma unroll
      for (int q = 0; q < 20; ++q) acc[q] = 0.f;
      const float4* wbx = (const float4*)(WbX + ((size_t)i * DN + j) * D);
      const float4* wax = (const float4*)(WaX + ((size_t)i * DN + j) * D);
      const float4* wtx = (const float4*)(WtX + ((size_t)i * DN + j) * D);
      const float4* win = (const float4*)(Win + ((size_t)i * DN + j) * D);
#pragma unroll
      for (int c = lane; c < D / 4; c += 64) {
        float4 wb = wbx[c], wa = wax[c], wt = wtx[c], wi = win[c];
#pragma unroll
        for (int b = 0; b < 4; ++b) {
          float4 sv = ((const float4*)(sS + b * D))[c];
          acc[0 + b]  = dot4(wb, sv, acc[0 + b]);
          acc[4 + b]  = dot4(wa, sv, acc[4 + b]);
          acc[8 + b]  = dot4(wt, sv, acc[8 + b]);
          acc[12 + b] = dot4(wi, sv, acc[12 + b]);
        }
      }
      if (doVU) {
        const float4* wbv = (const float4*)(WbV + ((size_t)i2 * DN + j) * DN);
#pragma unroll
        for (int c = lane; c < DN / 4; c += 64) {
          float4 wv = wbv[c];
#pragma unroll
          for (int b = 0; b < 4; ++b) {
            float4 vv = ((const float4*)(sX + b * DN))[c];
            acc[16 + b] = dot4(wv, vv, acc[16 + b]);
          }
        }
      }
      wred<20>(acc);
      if (lane == 0) {
        const float bb = b_beta[i * DN + j], ba = b_alpha[i * DN + j], bt = b_th[i * DN + j];
#pragma unroll
        for (int b = 0; b < 4; ++b) {
          float gb = GV[((size_t)(par_r * 3 + 0) * B + b) * DN + j];
          float ga = GV[((size_t)(par_r * 3 + 1) * B + b) * DN + j];
          float gt = GV[((size_t)(par_r * 3 + 2) * B + b) * DN + j];
          float beta = sigf(acc[0 + b] + gb + bb);
          float alpha = sigf(acc[4 + b] + ga + ba);
          float vth = 0.1f + softplusf(acc[8 + b] + gt + bt);
          float Vold = V[((size_t)i * B + b) * DN + j];
          float Vn = beta * Vold + alpha * acc[12 + b];
          float spike = (Vn - vth >= 0.0f) ? 1.0f : 0.0f;
          V[((size_t)i * B + b) * DN + j] = Vn - spike * vth;
          sp[b * DN + j] = spike;
          if (doVU) GV[((size_t)(par_w * 3 + 0) * B + b) * DN + j] = acc[16 + b];
        }
      }
    }
    gbar(bar, ++epoch);

    // ================= PHASE B: phase2(i)+WaV(i2) | WaV/WtV(i2) =================
    if (gw < 1024) {
      // PU blocks (0..255): sS still holds s_read from phase A; restage sX = sp.
      for (int idx = threadIdx.x; idx < (B * DN) / 4; idx += 256)
        ((float4*)sX)[idx] = ((const float4*)sp)[idx];
      __syncthreads();
      const int d = gw;
      // [0..3]=gate [4..7]=skip [8..11]=out [12..15]=WaV(i2) row d
      float acc[16];
#pragma unroll
      for (int q = 0; q < 16; ++q) acc[q] = 0.f;
      const float4* wg = (const float4*)(Wgate + ((size_t)i * D + d) * D);
      const float4* wk = (const float4*)(Wskip + ((size_t)i * D + d) * D);
#pragma unroll
      for (int c = lane; c < D / 4; c += 64) {
        float4 g = wg[c], k = wk[c];
#pragma unroll
        for (int b = 0; b < 4; ++b) {
          float4 sv = ((const float4*)(sS + b * D))[c];
          acc[0 + b] = dot4(g, sv, acc[0 + b]);
          acc[4 + b] = dot4(k, sv, acc[4 + b]);
        }
      }
      const float4* wo = (const float4*)(Wout + ((size_t)i * D + d) * DN);
#pragma unroll
      for (int c = lane; c < DN / 4; c += 64) {
        float4 o = wo[c];
#pragma unroll
        for (int b = 0; b < 4; ++b) {
          float4 pv = ((const float4*)(sX + b * DN))[c];
          acc[8 + b] = dot4(o, pv, acc[8 + b]);
        }
      }
      if (doVU) {
        const float4* wav = (const float4*)(WaV + ((size_t)i2 * DN + d) * DN);
        const float4* vg = (const float4*)(V + (size_t)i2 * B * DN);  // L2-hot broadcast
#pragma unroll
        for (int c = lane; c < DN / 4; c += 64) {
          float4 wv = wav[c];
#pragma unroll
          for (int b = 0; b < 4; ++b) {
            float4 vv = vg[b * (DN / 4) + c];
            acc[12 + b] = dot4(wv, vv, acc[12 + b]);
          }
        }
      }
      wred<16>(acc);
      if (lane == 0) {
        float pl = sigf(plif_w[i]);
        float ovth = out_vth[i];
        float bw = ldexpf(1.0f, -(kk + 1));
        float* s_write = sbuf + (size_t)((n + 1) & 1) * B * D;
#pragma unroll
        for (int b = 0; b < 4; ++b) {
          float g = sigf(acc[0 + b]);
          float cur = fmaf(g, acc[8 + b], acc[4 + b]);
          float uo = u[((size_t)i * B + b) * D + d];
          float un = uo + (cur - uo) * pl;
          float so = (un - ovth >= 0.0f) ? 1.0f : 0.0f;
          u[((size_t)i * B + b) * D + d] = (1.0f - so) * un;
          if (i < 3) {
            s_write[b * D + d] = so;
          } else {
            dec[b] = fmaf(so, bw, dec[b]);  // fused decode (bit-weighted sum)
            if (kk == 7) {
              decoded[((size_t)t * B + b) * D + d] = dec[b];
              dec[b] = 0.f;
            }
          }
          if (doVU) GV[((size_t)(par_w * 3 + 1) * B + b) * DN + d] = acc[12 + b];
        }
      }
    } else if (doVU) {
      // VU blocks (256..511): sX still holds V[i2] from phase A (untouched).
      const int v = gw - 1024;   // 0..1023
      const int ja = 1024 + v;
      // [0..3]=WaV[ja] [4..7]=WtV[v] [8..11]=WtV[ja]
      float acc[12];
#pragma unroll
      for (int q = 0; q < 12; ++q) acc[q] = 0.f;
      const float4* w0 = (const float4*)(WaV + ((size_t)i2 * DN + ja) * DN);
      const float4* w1 = (const float4*)(WtV + ((size_t)i2 * DN + v) * DN);
      const float4* w2 = (const float4*)(WtV + ((size_t)i2 * DN + ja) * DN);
#pragma unroll
      for (int c = lane; c < DN / 4; c += 64) {
        float4 a0 = w0[c], a1 = w1[c], a2 = w2[c];
#pragma unroll
        for (int b = 0; b < 4; ++b) {
          float4 vv = ((const float4*)(sX + b * DN))[c];
          acc[0 + b] = dot4(a0, vv, acc[0 + b]);
          acc[4 + b] = dot4(a1, vv, acc[4 + b]);
          acc[8 + b] = dot4(a2, vv, acc[8 + b]);
        }
      }
      wred<12>(acc);
      if (lane == 0) {
#pragma unroll
        for (int b = 0; b < 4; ++b) {
          GV[((size_t)(par_w * 3 + 1) * B + b) * DN + ja] = acc[0 + b];
          GV[((size_t)(par_w * 3 + 2) * B + b) * DN + v] = acc[4 + b];
          GV[((size_t)(par_w * 3 + 2) * B + b) * DN + ja] = acc[8 + b];
        }
      }
    }
    gbar(bar, ++epoch);
  }
}

// ---------------- dec GEMM: hh_pre = decoded @ dec_W.T + dec_b  (64 x D) ----------------
__global__ __launch_bounds__(256) void decgemm_kernel(
    const float* __restrict__ decoded,  // (64, D)
    const float* __restrict__ dec_W,    // (D, D)
    const float* __restrict__ dec_b, float* __restrict__ hh_pre) {
  __shared__ float sDec[16 * D];  // 64KB
  const int g = blockIdx.x & 3;   // row group (16 rows)
  for (int idx = threadIdx.x; idx < (16 * D) / 4; idx += 256)
    ((float4*)sDec)[idx] = ((const float4*)(decoded + (size_t)g * 16 * D))[idx];
  __syncthreads();

  const int lane = threadIdx.x & 63;
  const int d = (blockIdx.x >> 2) * 4 + (threadIdx.x >> 6);  // 0..1023
  float acc[16];
#pragma unroll
  for (int q = 0; q < 16; ++q) acc[q] = 0.f;
  const float4* wrow = (const float4*)(dec_W + (size_t)d * D);
  for (int c = lane; c < D / 4; c += 64) {
    float4 w = wrow[c];
#pragma unroll
    for (int r = 0; r < 16; ++r) {
      float4 x = ((const float4*)(sDec + r * D))[c];
      acc[r] = fmaf(w.x, x.x, fmaf(w.y, x.y, fmaf(w.z, x.z, fmaf(w.w, x.w, acc[r]))));
    }
  }
  wred<16>(acc);
  if (lane == 0) {
    float bb = dec_b[d];
#pragma unroll
    for (int r = 0; r < 16; ++r) hh_pre[(size_t)(g * 16 + r) * D + d] = acc[r] + bb;
  }
}

// ---------------- RMSNorm per row ----------------
__global__ __launch_bounds__(256) void rmsnorm_kernel(const float* __restrict__ hh_pre,
                                                      const float* __restrict__ norm_w,
                                                      float* __restrict__ hh) {
  const int r = blockIdx.x;  // 0..63
  const int lane = threadIdx.x & 63, w = threadIdx.x >> 6;
  __shared__ float red[4];
  float ss = 0.f;
  for (int d = threadIdx.x; d < D; d += 256) {
    float v = hh_pre[(size_t)r * D + d];
    ss = fmaf(v, v, ss);
  }
#pragma unroll
  for (int m = 1; m < 64; m <<= 1) ss += __shfl_xor(ss, m, 64);
  if (lane == 0) red[w] = ss;
  __syncthreads();
  float tot = red[0] + red[1] + red[2] + red[3];
  float scale = rsqrtf(tot * (1.0f / D) + 1e-6f);
  for (int d = threadIdx.x; d < D; d += 256)
    hh[(size_t)r * D + d] = norm_w[d] * (hh_pre[(size_t)r * D + d] * scale);
}

// ---------------- LM head: out[b,t,v] += hh[t*B+b,:] . embed[v,:] ----------------
__device__ __forceinline__ unsigned int bf16rn(float f) {
  unsigned int x = __float_as_uint(f);
  return (x + 0x7fffu + ((x >> 16) & 1u)) >> 16;
}

__global__ __launch_bounds__(256) void lmhead_kernel(
    const float* __restrict__ hh,     // (64, D), row = t*B + b
    const float* __restrict__ embed,  // (VOCAB, D)
    float* __restrict__ out) {        // (B, S, VOCAB), pre-zeroed
  __shared__ unsigned int sH[(D / 4) * 64];  // 64KB: bf16x2 of half the D range, [d2][row]
  const int half = blockIdx.x & 1;
  const int vblk = blockIdx.x >> 1;  // 0..255
  const int d0 = half * (D / 2);
  for (int e = threadIdx.x; e < (D / 4) * 64; e += 256) {
    int d2 = e >> 6, r = e & 63;
    float f0 = hh[(size_t)r * D + d0 + 2 * d2];
    float f1 = hh[(size_t)r * D + d0 + 2 * d2 + 1];
    sH[e] = bf16rn(f0) | (bf16rn(f1) << 16);
  }
  __syncthreads();

  const int lane = threadIdx.x & 63;
  const int wave = (vblk << 2) + (threadIdx.x >> 6);  // 0..1023
  for (int v = wave; v < VOCAB; v += 1024) {
    const float4* erow = (const float4*)(embed + (size_t)v * D + d0);
    float acc = 0.f;
#pragma unroll 4
    for (int c = 0; c < (D / 2) / 4; ++c) {  // 128 iters
      float4 e4 = erow[c];  // wave-uniform address (broadcast)
      unsigned int p0 = sH[(c * 2) * 64 + lane];
      unsigned int p1 = sH[(c * 2 + 1) * 64 + lane];
      float h0 = __uint_as_float(p0 << 16);
      float h1 = __uint_as_float(p0 & 0xffff0000u);
      float h2 = __uint_as_float(p1 << 16);
      float h3 = __uint_as_float(p1 & 0xffff0000u);
      acc = fmaf(e4.x, h0, fmaf(e4.y, h1, fmaf(e4.z, h2, fmaf(e4.w, h3, acc))));
    }
    int tt = lane >> 2, b = lane & 3;  // row = lane = t*B + b
    atomicAdd(&out[((size_t)b * S + tt) * VOCAB + v], acc);
  }
}

extern "C" void kernel_launch(void* const* d_in, const int* in_sizes, int n_in,
                              void* d_out, int out_size, void* d_ws, size_t ws_size,
                              hipStream_t stream) {
  const int* token_ids = (const int*)d_in[0];
  const float* embed   = (const float*)d_in[1];
  const float* norm_w  = (const float*)d_in[2];
  const float* enc_W   = (const float*)d_in[3];
  const float* enc_b   = (const float*)d_in[4];
  const float* dec_W   = (const float*)d_in[5];
  const float* dec_b   = (const float*)d_in[6];
  const float* Win     = (const float*)d_in[7];
  const float* WbX     = (const float*)d_in[8];
  const float* WaX     = (const float*)d_in[9];
  const float* WtX     = (const float*)d_in[10];
  const float* WbV     = (const float*)d_in[11];
  const float* WaV     = (const float*)d_in[12];
  const float* WtV     = (const float*)d_in[13];
  const float* b_beta  = (const float*)d_in[14];
  const float* b_alpha = (const float*)d_in[15];
  const float* b_th    = (const float*)d_in[16];
  const float* Wgate   = (const float*)d_in[17];
  const float* Wskip   = (const float*)d_in[18];
  const float* Wout    = (const float*)d_in[19];
  const float* plif_w  = (const float*)d_in[20];
  const float* out_vth = (const float*)d_in[21];

  float* ws = (float*)d_ws;
  float* frames  = ws;                        // S*K*B*D = 524288
  float* sp      = frames + S * K * B * D;    // B*DN    = 8192
  float* sbuf    = sp + B * DN;               // 2*B*D   = 8192
  float* V       = sbuf + 2 * B * D;          // NB*B*DN = 32768   (zeroed)
  float* u       = V + NB * B * DN;           // NB*B*D  = 16384   (zeroed)
  float* GV      = u + NB * B * D;            // 2*3*B*DN= 49152   (zeroed)
  float* decoded = GV + 2 * 3 * B * DN;       // S*B*D   = 65536   (zeroed)
  int*   bar     = (int*)(decoded + S * B * D);  // 2048 ints      (zeroed)
  // frames is dead after snn_main: alias post-loop buffers onto it
  float* hh_pre  = frames;                    // S*B*D
  float* hh      = frames + S * B * D;        // S*B*D

  // single contiguous zero of V,u,GV,decoded,bar
  hipMemsetAsync(V, 0,
                 (size_t)(NB * B * DN + NB * B * D + 2 * 3 * B * DN + S * B * D) * sizeof(float) +
                 2048 * sizeof(int), stream);
  hipMemsetAsync(d_out, 0, (size_t)out_size * sizeof(float), stream);

  void* args[] = {(void*)&token_ids, (void*)&embed, (void*)&enc_W, (void*)&enc_b,
                  (void*)&Win, (void*)&WbX, (void*)&WaX, (void*)&WtX,
                  (void*)&WbV, (void*)&WaV, (void*)&WtV,
                  (void*)&b_beta, (void*)&b_alpha, (void*)&b_th,
                  (void*)&Wgate, (void*)&Wskip, (void*)&Wout,
                  (void*)&plif_w, (void*)&out_vth,
                  (void*)&frames, (void*)&sp, (void*)&sbuf,
                  (void*)&V, (void*)&u, (void*)&GV, (void*)&decoded, (void*)&bar};
  hipError_t err = hipLaunchCooperativeKernel((void*)snn_main, dim3(NBLK), dim3(256),
                                              args, 0, stream);
  if (err != hipSuccess) {
    // fallback: plain launch. 48KB LDS -> 3 blocks/CU capacity (768 >= 512), so
    // all 512 blocks are co-resident and the software barrier is safe.
    snn_main<<<dim3(NBLK), dim3(256), 0, stream>>>(
        token_ids, embed, enc_W, enc_b, Win, WbX, WaX, WtX, WbV, WaV, WtV,
        b_beta, b_alpha, b_th, Wgate, Wskip, Wout, plif_w, out_vth,
        frames, sp, sbuf, V, u, GV, decoded, bar);
  }

  decgemm_kernel<<<1024, 256, 0, stream>>>(decoded, dec_W, dec_b, hh_pre);
  rmsnorm_kernel<<<S * B, 256, 0, stream>>>(hh_pre, norm_w, hh);
  lmhead_kernel<<<512, 256, 0, stream>>>(hh, embed, (float*)d_out);
}